// Round 3
// baseline (558.915 us; speedup 1.0000x reference)
//
#include <hip/hip_runtime.h>
#include <hip/hip_cooperative_groups.h>

namespace cg = cooperative_groups;

#define NBLK 256
#define NTHR 1024

// Swizzled LDS index for the z-vector: +1 dword pad every 32 dwords.
// Lane-stride-4-dword reads then hit each bank exactly twice (free, m136).
__device__ __forceinline__ int zi(int c) { return c + (c >> 5); }

// ACT forward: one cooperative kernel, device-side halting loop.
// 256 blocks x 1024 thr = 4096 waves = one wave per row of H=4096.
// 1 block/CU (16 waves/CU) -> loosest cooperative co-residency.
__global__ __launch_bounds__(NTHR, 4) void act_kernel(
    const float* __restrict__ x, const float* __restrict__ s,
    const float* __restrict__ Wh, const float* __restrict__ bh,
    const float* __restrict__ Whalt, const float* __restrict__ bhalt,
    const float* __restrict__ Wo, const float* __restrict__ bo,
    float* __restrict__ out, float* __restrict__ ws)
{
    cg::grid_group grid = cg::this_grid();

    const int tid  = threadIdx.x;
    const int lane = tid & 63;
    const int wid  = tid >> 6;                  // wave in block, 0..15
    const int gw   = blockIdx.x * 16 + wid;     // row 0..4095
    const int gtid = blockIdx.x * NTHR + tid;

    float* buf0 = ws;            // new_state ping-pong, 4096 floats each
    float* buf1 = ws + 4096;

    __shared__ float zl[8450];   // z = [flag, x, state], swizzled via zi()
    __shared__ float red[16];

    // stage x and s into LDS z; flag=1 for step 0
    for (int k = tid; k < 4096; k += NTHR) zl[zi(1 + k)]    = x[k];
    for (int k = tid; k < 4096; k += NTHR) zl[zi(4097 + k)] = s[k];
    if (tid == 0) zl[0] = 1.0f;
    __syncthreads();             // block-local only; first grid.sync is in-loop

    const float  bhalt0 = bhalt[0];
    const float* WhR    = Wh + (size_t)gw * 8193;
    const float* WoR    = Wo + (size_t)gw * 4096;
    const float  bh_r   = bh[gw];
    const float  bo_r   = bo[gw];

    float cum = 0.0f, ponder = 0.0f;
    float accO = 0.0f, accH = 0.0f;             // register-resident outputs

    for (int i = 0; i < 128; ++i) {
        float* nsG = (i & 1) ? buf1 : buf0;     // this step's new_state (global)

        // ---- phase A: new_state[gw] = Wh[gw] @ z + bh[gw]
        // Row gw is 16B-aligned starting at column c0 = (-gw) mod 4.
        float acc = 0.0f;
        const int c0 = (4 - (gw & 3)) & 3;
        if (lane < c0) acc += WhR[lane] * zl[zi(lane)];          // peel (<=3 cols)
        const int n4 = (8193 - c0) >> 2;
        const float4* W4 = reinterpret_cast<const float4*>(WhR + c0);
        #pragma unroll 8
        for (int j = lane; j < n4; j += 64) {
            float4 wv = W4[j];
            int c = c0 + 4 * j;
            acc += wv.x * zl[zi(c)];
            acc += wv.y * zl[zi(c + 1)];
            acc += wv.z * zl[zi(c + 2)];
            acc += wv.w * zl[zi(c + 3)];
        }
        for (int c = c0 + 4 * n4 + lane; c < 8193; c += 64)      // tail (<=3 cols)
            acc += WhR[c] * zl[zi(c)];
        #pragma unroll
        for (int off = 32; off > 0; off >>= 1) acc += __shfl_xor(acc, off, 64);
        const float nsval = acc + bh_r;          // all lanes hold it
        if (lane == 0) nsG[gw] = nsval;
        grid.sync();

        // ---- stage new_state into LDS z + halt partial dot (fused)
        float part = 0.0f;
        #pragma unroll
        for (int t = 0; t < 4; ++t) {
            int k = tid + t * NTHR;
            float v = nsG[k];
            zl[zi(4097 + k)] = v;
            part += Whalt[k] * v;
        }
        #pragma unroll
        for (int off = 32; off > 0; off >>= 1) part += __shfl_xor(part, off, 64);
        if (lane == 0) red[wid] = part;
        __syncthreads();                         // z staged + red ready
        float logit = bhalt0;
        #pragma unroll
        for (int j = 0; j < 16; ++j) logit += red[j];  // identical everywhere
        const float p         = 1.0f / (1.0f + expf(-logit));
        const bool  will_halt = (cum + p >= 0.99f) || (i == 127);
        const float w         = will_halt ? (1.0f - cum) : p;

        // ---- phase C: out += w*(Wo@ns + bo); hid += w*ns   (ns from LDS)
        float acc2 = 0.0f;
        const float4* Wo4 = reinterpret_cast<const float4*>(WoR);
        #pragma unroll 8
        for (int j = lane; j < 1024; j += 64) {
            float4 wv = Wo4[j];
            int c = 4097 + 4 * j;
            acc2 += wv.x * zl[zi(c)]     + wv.y * zl[zi(c + 1)]
                  + wv.z * zl[zi(c + 2)] + wv.w * zl[zi(c + 3)];
        }
        #pragma unroll
        for (int off = 32; off > 0; off >>= 1) acc2 += __shfl_xor(acc2, off, 64);
        accO += w * (acc2 + bo_r);
        accH += w * nsval;

        if (will_halt) {                          // uniform across the grid
            ponder = (float)i + 1.0f + (1.0f - cum);
            break;
        }
        cum += p;
        if (i == 0 && tid == 0) zl[0] = 0.0f;     // flag off after step 0
        __syncthreads();                          // protect zl[0] clear
    }

    if (lane == 0) { out[gw] = accO; out[4096 + gw] = accH; }
    if (gtid == 0) out[8192] = ponder;
}

extern "C" void kernel_launch(void* const* d_in, const int* in_sizes, int n_in,
                              void* d_out, int out_size, void* d_ws, size_t ws_size,
                              hipStream_t stream) {
    const float* x     = (const float*)d_in[0];
    const float* s     = (const float*)d_in[1];
    const float* Wh    = (const float*)d_in[2];
    const float* bh    = (const float*)d_in[3];
    const float* Whalt = (const float*)d_in[4];
    const float* bhalt = (const float*)d_in[5];
    const float* Wo    = (const float*)d_in[6];
    const float* bo    = (const float*)d_in[7];
    float* out = (float*)d_out;
    float* wsp = (float*)d_ws;

    void* args[] = { (void*)&x, (void*)&s, (void*)&Wh, (void*)&bh,
                     (void*)&Whalt, (void*)&bhalt, (void*)&Wo, (void*)&bo,
                     (void*)&out, (void*)&wsp };
    hipLaunchCooperativeKernel((void*)act_kernel, dim3(NBLK), dim3(NTHR),
                               args, 0, stream);
}

// Round 6
// 456.380 us; speedup vs baseline: 1.2247x; 1.2247x over previous
//
#include <hip/hip_runtime.h>
#include <hip/hip_cooperative_groups.h>

namespace cg = cooperative_groups;

#define NBLK 512
#define NTHR 1024

// Swizzled LDS index: +1 dword pad every 32 dwords -> stride-4-dword lane
// access hits each bank exactly 2x (2-way is free, m136).
__device__ __forceinline__ int zi(int c) { return c + (c >> 5); }

__device__ __forceinline__ unsigned short f2bf(float f) {   // RNE f32->bf16
    unsigned int u = __float_as_uint(f);
    return (unsigned short)((u + 0x7fffu + ((u >> 16) & 1u)) >> 16);
}
__device__ __forceinline__ float bfLO(unsigned int v) { return __uint_as_float(v << 16); }
__device__ __forceinline__ float bfHI(unsigned int v) { return __uint_as_float(v & 0xffff0000u); }

// ===================== main kernel: 2x occupancy, Wh f32 (halt-exact), Wo bf16 =====================
// 512 blocks x 1024 thr = 8192 waves = 2 waves/row (column halves).
// LDS 16.6KB/block -> 2 blocks/CU = 32 waves/CU. blocks 0..255 = half 0
// (cols [0,4097): flag+x, static LDS), 256..511 = half 1 (cols [4097,8193):
// state LDS, refreshed for free during the halt pass).
__global__ __launch_bounds__(NTHR, 8) void act_main(
    const float* __restrict__ x, const float* __restrict__ s,
    const float* __restrict__ Wh, const float* __restrict__ bh,
    const float* __restrict__ Whalt, const float* __restrict__ bhalt,
    const float* __restrict__ Wo, const float* __restrict__ bo,
    float* __restrict__ out, unsigned short* __restrict__ wWo,
    float* __restrict__ pbE, float* __restrict__ pbO, float* __restrict__ endO)
{
    cg::grid_group grid = cg::this_grid();
    const int tid  = threadIdx.x;
    const int lane = tid & 63;
    const int wid  = tid >> 6;
    const int half = blockIdx.x >> 8;                  // column half 0/1
    const int row  = ((blockIdx.x & 255) << 4) + wid;  // 0..4095

    __shared__ float zb[4225];   // half0: z[0..4096]; half1: state/ns[0..4095]
    __shared__ float red[16];

    if (half == 0) {
        if (tid == 0) zb[0] = 1.0f;                    // flag (step 0)
        for (int k = tid; k < 4096; k += NTHR) zb[zi(1 + k)] = x[k];
    } else {
        for (int k = tid; k < 4096; k += NTHR) zb[zi(k)] = s[k];
    }
    __syncthreads();

    const float bhalt0 = bhalt[0];
    const float* WhR = Wh + (size_t)row * 8193;
    const float* WoR = Wo + (size_t)row * 4096;
    unsigned short* worow = wWo + (size_t)row * 4096;

    // phase-A column range for this half; 16B-aligned via peel
    const int start = half ? 4097 : 0;
    const int end   = half ? 8193 : 4097;
    const int zoff  = half ? 4097 : 0;
    const int pre   = (4 - ((row + half) & 3)) & 3;    // (row*8193+start)%4 fix
    const int cs    = start + pre;
    const int n4    = (end - cs) >> 2;
    const int tail0 = cs + 4 * n4;
    const float4* W4  = reinterpret_cast<const float4*>(WhR + cs);
    const float4* bh4 = reinterpret_cast<const float4*>(bh);
    const float4* wh4 = reinterpret_cast<const float4*>(Whalt);

    float cum = 0.f, ponder = 0.f, accO = 0.f, accH = 0.f, wsum = 0.f;

    for (int i = 0; i < 128; ++i) {
        float* pbCur = (i & 1) ? pbO : pbE;            // parity double-buffer

        // ---- phase A: partial = Wh[row, start:end] @ z[start:end]  (f32 exact)
        float a0 = 0.f, a1 = 0.f, a2 = 0.f, a3 = 0.f;
        if (lane < pre) a0 = WhR[start + lane] * zb[zi(start + lane - zoff)];
        #pragma unroll 4
        for (int j = lane; j < n4; j += 64) {
            float4 wv = W4[j];
            int c = cs + 4 * j - zoff;
            a0 += wv.x * zb[zi(c)];
            a1 += wv.y * zb[zi(c + 1)];
            a2 += wv.z * zb[zi(c + 2)];
            a3 += wv.w * zb[zi(c + 3)];
        }
        for (int c = tail0 + lane; c < end; c += 64)
            a0 += WhR[c] * zb[zi(c - zoff)];
        float acc = (a0 + a1) + (a2 + a3);
        #pragma unroll
        for (int off = 32; off; off >>= 1) acc += __shfl_xor(acc, off, 64);
        if (lane == 0) pbCur[(half << 12) + row] = acc;
        grid.sync();                                   // the only grid sync/step

        // ---- phase B: ns = pb0+pb1+bh; halt dot (redundant, identical per block)
        const float4* p0v = reinterpret_cast<const float4*>(pbCur);
        const float4* p1v = reinterpret_cast<const float4*>(pbCur + 4096);
        float4 q0 = p0v[tid], q1 = p1v[tid], bb = bh4[tid], hw = wh4[tid];
        float4 nsv;
        nsv.x = q0.x + q1.x + bb.x;  nsv.y = q0.y + q1.y + bb.y;
        nsv.z = q0.z + q1.z + bb.z;  nsv.w = q0.w + q1.w + bb.w;
        if (half) {                                    // free state refresh
            int c = 4 * tid;
            zb[zi(c)]   = nsv.x; zb[zi(c+1)] = nsv.y;
            zb[zi(c+2)] = nsv.z; zb[zi(c+3)] = nsv.w;
        }
        float part = hw.x*nsv.x + hw.y*nsv.y + hw.z*nsv.z + hw.w*nsv.w;
        #pragma unroll
        for (int off = 32; off; off >>= 1) part += __shfl_xor(part, off, 64);
        if (lane == 0) red[wid] = part;
        __syncthreads();                               // red + zb(ns) ready
        float logit = bhalt0;
        #pragma unroll
        for (int j2 = 0; j2 < 16; ++j2) logit += red[j2];   // identical everywhere
        const float p         = 1.0f / (1.0f + expf(-logit));
        const bool  will_halt = (cum + p >= 0.99f) || (i == 127);
        const float w         = will_halt ? (1.0f - cum) : p;

        // ---- phase C: out-partial = Wo[row, half*2048:+2048] @ ns
        float b0 = 0.f, b1 = 0.f, b2 = 0.f, b3 = 0.f;
        if (i == 0) {
            // f32 read + fused bf16 convert/store (Wo never touches halting)
            const float4* Wo4 = reinterpret_cast<const float4*>(WoR);
            uint2* wst = reinterpret_cast<uint2*>(worow);
            const int j0 = half << 9;
            #pragma unroll 4
            for (int j = j0 + lane; j < j0 + 512; j += 64) {
                float4 wv = Wo4[j];
                float nx, ny, nz, nw;
                if (half) {
                    int c = 4 * j;
                    nx = zb[zi(c)];   ny = zb[zi(c+1)];
                    nz = zb[zi(c+2)]; nw = zb[zi(c+3)];
                } else {
                    float4 u0 = p0v[j], u1 = p1v[j], ub = bh4[j];
                    nx = u0.x+u1.x+ub.x; ny = u0.y+u1.y+ub.y;
                    nz = u0.z+u1.z+ub.z; nw = u0.w+u1.w+ub.w;
                }
                b0 += wv.x*nx; b1 += wv.y*ny; b2 += wv.z*nz; b3 += wv.w*nw;
                uint2 pk;
                pk.x = (unsigned)f2bf(wv.x) | ((unsigned)f2bf(wv.y) << 16);
                pk.y = (unsigned)f2bf(wv.z) | ((unsigned)f2bf(wv.w) << 16);
                wst[j] = pk;
            }
        } else {
            const uint4* W8 = reinterpret_cast<const uint4*>(worow);
            const int j0 = half << 8;
            #pragma unroll 2
            for (int j = j0 + lane; j < j0 + 256; j += 64) {
                uint4 v = W8[j];
                float n0,n1,n2,n3,m0,m1,m2,m3;
                if (half) {
                    int c = 8 * j;
                    n0 = zb[zi(c)];   n1 = zb[zi(c+1)];
                    n2 = zb[zi(c+2)]; n3 = zb[zi(c+3)];
                    m0 = zb[zi(c+4)]; m1 = zb[zi(c+5)];
                    m2 = zb[zi(c+6)]; m3 = zb[zi(c+7)];
                } else {
                    int jj = 2 * j;
                    float4 u0 = p0v[jj],   u1 = p1v[jj],   ub = bh4[jj];
                    float4 v0 = p0v[jj+1], v1 = p1v[jj+1], vb = bh4[jj+1];
                    n0 = u0.x+u1.x+ub.x; n1 = u0.y+u1.y+ub.y;
                    n2 = u0.z+u1.z+ub.z; n3 = u0.w+u1.w+ub.w;
                    m0 = v0.x+v1.x+vb.x; m1 = v0.y+v1.y+vb.y;
                    m2 = v0.z+v1.z+vb.z; m3 = v0.w+v1.w+vb.w;
                }
                b0 += bfLO(v.x)*n0; b1 += bfHI(v.x)*n1;
                b2 += bfLO(v.y)*n2; b3 += bfHI(v.y)*n3;
                b0 += bfLO(v.z)*m0; b1 += bfHI(v.z)*m1;
                b2 += bfLO(v.w)*m2; b3 += bfHI(v.w)*m3;
            }
        }
        float acc2 = (b0 + b1) + (b2 + b3);
        #pragma unroll
        for (int off = 32; off; off >>= 1) acc2 += __shfl_xor(acc2, off, 64);
        accO += w * acc2;
        wsum += w;
        if (half && lane == 0) accH += w * zb[zi(row)];

        if (will_halt) {                               // uniform across the grid
            ponder = (float)i + 1.0f + (1.0f - cum);
            break;
        }
        cum += p;
        if (i == 0) {
            if (half == 0 && tid == 0) zb[0] = 0.0f;   // flag off after step 0
            __syncthreads();
        }
    }

    if (lane == 0) endO[(half << 12) + row] = accO;
    grid.sync();
    if (half == 0 && lane == 0) out[row] = endO[row] + endO[4096 + row] + wsum * bo[row];
    if (half == 1 && lane == 0) out[4096 + row] = accH;
    if (blockIdx.x == 0 && tid == 0) out[8192] = ponder;
}

// ===================== f32 fallback (round-2 kernel, known-good 476us) =====================
__global__ __launch_bounds__(1024, 4) void act_f32(
    const float* __restrict__ x, const float* __restrict__ s,
    const float* __restrict__ Wh, const float* __restrict__ bh,
    const float* __restrict__ Whalt, const float* __restrict__ bhalt,
    const float* __restrict__ Wo, const float* __restrict__ bo,
    float* __restrict__ out, float* __restrict__ ws)
{
    cg::grid_group grid = cg::this_grid();
    const int tid  = threadIdx.x;
    const int lane = tid & 63;
    const int wid  = tid >> 6;
    const int gw   = blockIdx.x * 16 + wid;
    const int gtid = blockIdx.x * 1024 + tid;

    float* buf0 = ws;
    float* buf1 = ws + 4096;

    __shared__ float xl[4096];
    __shared__ float red[16];

    for (int k = tid; k < 4096; k += 1024) xl[k] = x[k];
    if (gtid < 8193) out[gtid] = 0.0f;
    if (gtid < 4096) buf1[gtid] = s[gtid];
    grid.sync();

    const float  bhalt0 = bhalt[0];
    const float* WhR = Wh + (size_t)gw * 8193;
    const float* WoR = Wo + (size_t)gw * 4096;
    const float  bh_r = bh[gw];
    const float  bo_r = bo[gw];

    float cum = 0.0f, ponder = 0.0f;

    for (int i = 0; i < 128; ++i) {
        const float* st = (i & 1) ? buf0 : buf1;
        float*       ns = (i & 1) ? buf1 : buf0;

        float acc = 0.0f;
        #pragma unroll 8
        for (int k = lane; k < 4096; k += 64) acc += WhR[1 + k] * xl[k];
        #pragma unroll 8
        for (int k = lane; k < 4096; k += 64) acc += WhR[4097 + k] * st[k];
        #pragma unroll
        for (int off = 32; off; off >>= 1) acc += __shfl_xor(acc, off, 64);
        if (lane == 0) {
            float v = acc + bh_r;
            if (i == 0) v += WhR[0];
            ns[gw] = v;
        }
        grid.sync();

        float part = 0.0f;
        #pragma unroll
        for (int k = tid; k < 4096; k += 1024) part += Whalt[k] * ns[k];
        #pragma unroll
        for (int off = 32; off; off >>= 1) part += __shfl_xor(part, off, 64);
        if (lane == 0) red[wid] = part;
        __syncthreads();
        float logit = bhalt0;
        #pragma unroll
        for (int j = 0; j < 16; ++j) logit += red[j];
        const float p         = 1.0f / (1.0f + expf(-logit));
        const bool  will_halt = (cum + p >= 0.99f) || (i == 127);
        const float w         = will_halt ? (1.0f - cum) : p;

        float acc2 = 0.0f;
        const float4* W4 = reinterpret_cast<const float4*>(WoR);
        const float4* n4 = reinterpret_cast<const float4*>(ns);
        #pragma unroll 8
        for (int k = lane; k < 1024; k += 64) {
            float4 wv = W4[k];
            float4 nv = n4[k];
            acc2 += wv.x * nv.x + wv.y * nv.y + wv.z * nv.z + wv.w * nv.w;
        }
        #pragma unroll
        for (int off = 32; off; off >>= 1) acc2 += __shfl_xor(acc2, off, 64);
        if (lane == 0) {
            out[gw]        += w * (acc2 + bo_r);
            out[4096 + gw] += w * ns[gw];
        }

        if (will_halt) { ponder = (float)i + 1.0f + (1.0f - cum); break; }
        cum += p;
    }
    if (gtid == 0) out[8192] = ponder;
}

extern "C" void kernel_launch(void* const* d_in, const int* in_sizes, int n_in,
                              void* d_out, int out_size, void* d_ws, size_t ws_size,
                              hipStream_t stream) {
    const float* x     = (const float*)d_in[0];
    const float* s     = (const float*)d_in[1];
    const float* Wh    = (const float*)d_in[2];
    const float* bh    = (const float*)d_in[3];
    const float* Whalt = (const float*)d_in[4];
    const float* bhalt = (const float*)d_in[5];
    const float* Wo    = (const float*)d_in[6];
    const float* bo    = (const float*)d_in[7];
    float* out = (float*)d_out;

    const size_t woBytes = (size_t)4096 * 4096 * 2;            // bf16 Wo copy
    const size_t need    = woBytes + (size_t)3 * 8192 * 4;     // + pbE/pbO/endO

    unsigned short* wWo = (unsigned short*)d_ws;
    float* pbE  = (float*)((char*)d_ws + woBytes);
    float* pbO  = pbE + 8192;
    float* endO = pbO + 8192;

    int nb = 0;
    hipError_t qe = hipOccupancyMaxActiveBlocksPerMultiprocessor(&nb, act_main, NTHR, 0);
    if (qe == hipSuccess && nb >= 2 && ws_size >= need) {
        void* args[] = { (void*)&x, (void*)&s, (void*)&Wh, (void*)&bh,
                         (void*)&Whalt, (void*)&bhalt, (void*)&Wo, (void*)&bo,
                         (void*)&out, (void*)&wWo, (void*)&pbE, (void*)&pbO,
                         (void*)&endO };
        hipError_t e = hipLaunchCooperativeKernel((void*)act_main, dim3(NBLK),
                                                  dim3(NTHR), args, 0, stream);
        if (e == hipSuccess) return;
    }
    // fallback: proven round-2 kernel
    float* wsp = (float*)d_ws;
    void* args2[] = { (void*)&x, (void*)&s, (void*)&Wh, (void*)&bh,
                      (void*)&Whalt, (void*)&bhalt, (void*)&Wo, (void*)&bo,
                      (void*)&out, (void*)&wsp };
    hipLaunchCooperativeKernel((void*)act_f32, dim3(256), dim3(1024),
                               args2, 0, stream);
}

// Round 7
// 307.564 us; speedup vs baseline: 1.8172x; 1.4839x over previous
//
#include <hip/hip_runtime.h>
#include <hip/hip_cooperative_groups.h>

namespace cg = cooperative_groups;

#define K_PRE 8          // pre-launched device-halting steps (bench data T~3-4)

// ---- ws float-offset map (all float4-aligned) ----
#define O_WSUM    3
#define O_PONDER  2
#define O_W       32     // w[i], 128 slots
#define O_CUMARR  192    // cum after step i, per-step (race-free)
#define O_DONEARR 352    // done after step i, per-step
#define O_NS0     512
#define O_NS1     4608
#define O_PB      8704   // 8192 partials
#define O_ACCO    16896  // 8192 (two half-partials of out head)
#define O_ACCH    25088  // 4096
#define WS_FLOATS 29184

// Swizzled LDS index: +1 dword pad every 32 -> 2-way bank alias only (free).
__device__ __forceinline__ int zi(int c) { return c + (c >> 5); }

// ---------- init: reset ALL carried state (determinism w/ dirty ws) ----------
__global__ __launch_bounds__(256) void k_init(float* __restrict__ wsb) {
    int t = blockIdx.x * 256 + threadIdx.x;
    if (t < 512) wsb[t] = 0.0f;                       // scalars + w/cum/done arrays
    for (int k = t; k < 12288; k += gridDim.x * 256)  // accO(8192)+accH(4096)
        wsb[O_ACCO + k] = 0.0f;
}

// ---------- k_A: phase A of step i (+ fused phase C of step i-1) ----------
// 512 blocks x 1024 thr = 8192 waves = 2 waves/row (column halves).
// Plain launch: kernel boundary replaces grid.sync.
__global__ __launch_bounds__(1024) void k_A(
    int i, int aEnable,
    const float* __restrict__ statePrev,   // s (i==0) or ns[(i-1)&1]
    const float* __restrict__ x,
    const float* __restrict__ Wh, const float* __restrict__ Wo,
    float* __restrict__ wsb)
{
    const int tid  = threadIdx.x;
    const int lane = tid & 63;
    const int wid  = tid >> 6;
    const int half = blockIdx.x >> 8;                  // column half 0/1
    const int row  = ((blockIdx.x & 255) << 4) + wid;  // 0..4095

    __shared__ float zb[4225];

    const float doneIn = (i == 0) ? 0.0f : wsb[O_DONEARR + i - 1];

    // ---- phase A (exact r6 numerics -> identical halting trajectory)
    if (aEnable && doneIn == 0.0f) {
        if (half == 0) {
            if (tid == 0) zb[0] = (i == 0) ? 1.0f : 0.0f;   // flag column
            for (int k = tid; k < 4096; k += 1024) zb[zi(1 + k)] = x[k];
        } else {
            for (int k = tid; k < 4096; k += 1024) zb[zi(k)] = statePrev[k];
        }
        __syncthreads();

        const float* WhR  = Wh + (size_t)row * 8193;
        const int start = half ? 4097 : 0;
        const int end   = half ? 8193 : 4097;
        const int zoff  = half ? 4097 : 0;
        const int pre   = (4 - ((row + half) & 3)) & 3;
        const int cs    = start + pre;
        const int n4    = (end - cs) >> 2;
        const int tail0 = cs + 4 * n4;
        const float4* W4 = reinterpret_cast<const float4*>(WhR + cs);

        float a0 = 0.f, a1 = 0.f, a2 = 0.f, a3 = 0.f;
        if (lane < pre) a0 = WhR[start + lane] * zb[zi(start + lane - zoff)];
        #pragma unroll 4
        for (int j = lane; j < n4; j += 64) {
            float4 wv = W4[j];
            int c = cs + 4 * j - zoff;
            a0 += wv.x * zb[zi(c)];
            a1 += wv.y * zb[zi(c + 1)];
            a2 += wv.z * zb[zi(c + 2)];
            a3 += wv.w * zb[zi(c + 3)];
        }
        for (int c = tail0 + lane; c < end; c += 64)
            a0 += WhR[c] * zb[zi(c - zoff)];
        float acc = (a0 + a1) + (a2 + a3);
        #pragma unroll
        for (int off = 32; off; off >>= 1) acc += __shfl_xor(acc, off, 64);
        if (lane == 0) wsb[O_PB + (half << 12) + row] = acc;
    }

    // ---- fused phase C of step i-1: accO_half[row] += w[i-1] * (Wo half-row @ ns)
    if (i > 0) {
        const float wprev = wsb[O_W + (i - 1)];
        if (wprev != 0.0f) {
            const float4* Wo4 = reinterpret_cast<const float4*>(Wo + (size_t)row * 4096);
            const float4* ns4 = reinterpret_cast<const float4*>(statePrev);
            const int j0 = half << 9;
            float b0 = 0.f, b1 = 0.f, b2 = 0.f, b3 = 0.f;
            #pragma unroll 4
            for (int j = j0 + lane; j < j0 + 512; j += 64) {
                float4 wv = Wo4[j];
                float4 nv = ns4[j];
                b0 += wv.x * nv.x; b1 += wv.y * nv.y;
                b2 += wv.z * nv.z; b3 += wv.w * nv.w;
            }
            float acc2 = (b0 + b1) + (b2 + b3);
            #pragma unroll
            for (int off = 32; off; off >>= 1) acc2 += __shfl_xor(acc2, off, 64);
            if (lane == 0) wsb[O_ACCO + (half << 12) + row] += wprev * acc2;
        }
    }
}

// ---------- k_h: ns = pb0+pb1+bh; halt logit; w/cum/done/ponder; accH ----------
// 8 blocks x 1024 thr; every block computes the identical logit redundantly;
// block b writes slice tid in [128b,128b+128) of ns/accH. Per-step scalar
// slots (cum/done arrays) -> no intra-kernel scalar races.
__global__ __launch_bounds__(1024) void k_h(
    int i, const float* __restrict__ bh, const float* __restrict__ Whalt,
    const float* __restrict__ bhalt, float* __restrict__ wsb)
{
    const int tid  = threadIdx.x;
    const int lane = tid & 63;
    const int wid  = tid >> 6;
    __shared__ float red[16];

    const float doneIn = (i == 0) ? 0.0f : wsb[O_DONEARR + i - 1];
    if (doneIn != 0.0f) {
        if (blockIdx.x == 0 && tid == 0) {
            wsb[O_W + i] = 0.0f;
            wsb[O_DONEARR + i] = 1.0f;
        }
        return;
    }

    const float4* p0v = reinterpret_cast<const float4*>(wsb + O_PB);
    const float4* p1v = reinterpret_cast<const float4*>(wsb + O_PB + 4096);
    const float4* bh4 = reinterpret_cast<const float4*>(bh);
    const float4* wh4 = reinterpret_cast<const float4*>(Whalt);

    float4 q0 = p0v[tid], q1 = p1v[tid], bb = bh4[tid], hw = wh4[tid];
    float4 nsv;
    nsv.x = q0.x + q1.x + bb.x;  nsv.y = q0.y + q1.y + bb.y;
    nsv.z = q0.z + q1.z + bb.z;  nsv.w = q0.w + q1.w + bb.w;

    float part = hw.x*nsv.x + hw.y*nsv.y + hw.z*nsv.z + hw.w*nsv.w;
    #pragma unroll
    for (int off = 32; off; off >>= 1) part += __shfl_xor(part, off, 64);
    if (lane == 0) red[wid] = part;
    __syncthreads();
    float logit = bhalt[0];
    #pragma unroll
    for (int j = 0; j < 16; ++j) logit += red[j];      // identical everywhere

    const float cum       = (i == 0) ? 0.0f : wsb[O_CUMARR + i - 1];
    const float p         = 1.0f / (1.0f + expf(-logit));
    const bool  will_halt = (cum + p >= 0.99f) || (i == 127);
    const float w         = will_halt ? (1.0f - cum) : p;

    float* nsOut = wsb + ((i & 1) ? O_NS1 : O_NS0);
    if ((tid >> 7) == (int)blockIdx.x) {               // disjoint slices
        reinterpret_cast<float4*>(nsOut)[tid] = nsv;
        float4* aH = reinterpret_cast<float4*>(wsb + O_ACCH);
        float4 t = aH[tid];
        t.x += w * nsv.x; t.y += w * nsv.y; t.z += w * nsv.z; t.w += w * nsv.w;
        aH[tid] = t;
    }
    if (blockIdx.x == 0 && tid == 0) {
        wsb[O_W + i]       = w;
        wsb[O_CUMARR + i]  = cum + p;
        wsb[O_DONEARR + i] = will_halt ? 1.0f : 0.0f;
        wsb[O_WSUM]       += w;
        if (will_halt) wsb[O_PONDER] = (float)i + 1.0f + (1.0f - cum);
    }
}

// ---------- cooperative tail for hypothetical T > K_PRE (exits in ~5us here) ----------
__global__ __launch_bounds__(1024, 4) void k_tail(
    const float* __restrict__ x, const float* __restrict__ Wh,
    const float* __restrict__ bh, const float* __restrict__ Whalt,
    const float* __restrict__ bhalt, const float* __restrict__ Wo,
    float* __restrict__ wsb)
{
    cg::grid_group grid = cg::this_grid();
    if (wsb[O_DONEARR + K_PRE - 1] != 0.0f) return;    // uniform early exit

    const int tid  = threadIdx.x;
    const int lane = tid & 63;
    const int wid  = tid >> 6;
    const int gw   = blockIdx.x * 16 + wid;

    float* ns0 = wsb + O_NS0;
    float* ns1 = wsb + O_NS1;

    __shared__ float xl[4096];
    __shared__ float red[16];
    for (int k = tid; k < 4096; k += 1024) xl[k] = x[k];
    __syncthreads();

    const float* WhR  = Wh + (size_t)gw * 8193;
    const float4* Wo4 = reinterpret_cast<const float4*>(Wo + (size_t)gw * 4096);
    const float4* wh4 = reinterpret_cast<const float4*>(Whalt);
    const float bh_r  = bh[gw];
    const float bhalt0 = bhalt[0];

    float cum = wsb[O_CUMARR + K_PRE - 1];
    float accOl = 0.f, wsuml = 0.f, ponder = 0.f;

    for (int i = K_PRE; i < 128; ++i) {
        const float* st = (i & 1) ? ns0 : ns1;         // prev state
        float*      nsc = (i & 1) ? ns1 : ns0;

        float acc = 0.0f;
        #pragma unroll 8
        for (int k = lane; k < 4096; k += 64) acc += WhR[1 + k] * xl[k];
        #pragma unroll 8
        for (int k = lane; k < 4096; k += 64) acc += WhR[4097 + k] * st[k];
        #pragma unroll
        for (int off = 32; off; off >>= 1) acc += __shfl_xor(acc, off, 64);
        if (lane == 0) nsc[gw] = acc + bh_r;
        grid.sync();

        const float4* ns4 = reinterpret_cast<const float4*>(nsc);
        float4 nv = ns4[tid], hw = wh4[tid];
        float part = hw.x*nv.x + hw.y*nv.y + hw.z*nv.z + hw.w*nv.w;
        #pragma unroll
        for (int off = 32; off; off >>= 1) part += __shfl_xor(part, off, 64);
        if (lane == 0) red[wid] = part;
        __syncthreads();
        float logit = bhalt0;
        #pragma unroll
        for (int j = 0; j < 16; ++j) logit += red[j];
        const float p         = 1.0f / (1.0f + expf(-logit));
        const bool  will_halt = (cum + p >= 0.99f) || (i == 127);
        const float w         = will_halt ? (1.0f - cum) : p;

        if (blockIdx.x == 0) {                          // accH, vector-wide
            float4* aH = reinterpret_cast<float4*>(wsb + O_ACCH);
            float4 t = aH[tid];
            t.x += w*nv.x; t.y += w*nv.y; t.z += w*nv.z; t.w += w*nv.w;
            aH[tid] = t;
        }

        float b0 = 0.f, b1 = 0.f, b2 = 0.f, b3 = 0.f;   // full-row Wo dot
        #pragma unroll 4
        for (int j = lane; j < 1024; j += 64) {
            float4 wv = Wo4[j], qv = ns4[j];
            b0 += wv.x*qv.x; b1 += wv.y*qv.y; b2 += wv.z*qv.z; b3 += wv.w*qv.w;
        }
        float acc2 = (b0 + b1) + (b2 + b3);
        #pragma unroll
        for (int off = 32; off; off >>= 1) acc2 += __shfl_xor(acc2, off, 64);
        accOl += w * acc2;
        wsuml += w;

        if (will_halt) { ponder = (float)i + 1.0f + (1.0f - cum); break; }
        cum += p;
        grid.sync();   // WAR: next A-write target was only read pre-sync this iter
    }

    if (lane == 0) wsb[O_ACCO + gw] += accOl;
    if (blockIdx.x == 0 && tid == 0) {
        wsb[O_WSUM]  += wsuml;
        wsb[O_PONDER] = ponder;
    }
}

// ---------- finalize ----------
__global__ __launch_bounds__(256) void k_fin(
    const float* __restrict__ bo, float* __restrict__ out,
    const float* __restrict__ wsb)
{
    int r = blockIdx.x * 256 + threadIdx.x;            // 0..4095
    out[r]        = wsb[O_ACCO + r] + wsb[O_ACCO + 4096 + r] + wsb[O_WSUM] * bo[r];
    out[4096 + r] = wsb[O_ACCH + r];
    if (r == 0) out[8192] = wsb[O_PONDER];
}

extern "C" void kernel_launch(void* const* d_in, const int* in_sizes, int n_in,
                              void* d_out, int out_size, void* d_ws, size_t ws_size,
                              hipStream_t stream) {
    const float* x     = (const float*)d_in[0];
    const float* s     = (const float*)d_in[1];
    const float* Wh    = (const float*)d_in[2];
    const float* bh    = (const float*)d_in[3];
    const float* Whalt = (const float*)d_in[4];
    const float* bhalt = (const float*)d_in[5];
    const float* Wo    = (const float*)d_in[6];
    const float* bo    = (const float*)d_in[7];
    float* out = (float*)d_out;
    float* wsb = (float*)d_ws;

    float* ns0 = wsb + O_NS0;
    float* ns1 = wsb + O_NS1;

    k_init<<<48, 256, 0, stream>>>(wsb);

    for (int i = 0; i < K_PRE; ++i) {
        const float* prev = (i == 0) ? s : (((i - 1) & 1) ? ns1 : ns0);
        k_A<<<512, 1024, 0, stream>>>(i, 1, prev, x, Wh, Wo, wsb);
        k_h<<<8, 1024, 0, stream>>>(i, bh, Whalt, bhalt, wsb);
    }
    // phase C of step K_PRE-1 (A disabled)
    {
        const float* prev = ((K_PRE - 1) & 1) ? ns1 : ns0;
        k_A<<<512, 1024, 0, stream>>>(K_PRE, 0, prev, x, Wh, Wo, wsb);
    }
    // cooperative tail for T > K_PRE (instant exit on real data)
    {
        void* args[] = { (void*)&x, (void*)&Wh, (void*)&bh, (void*)&Whalt,
                         (void*)&bhalt, (void*)&Wo, (void*)&wsb };
        hipLaunchCooperativeKernel((void*)k_tail, dim3(256), dim3(1024),
                                   args, 0, stream);
    }
    k_fin<<<16, 256, 0, stream>>>(bo, out, wsb);
}

// Round 8
// 256.810 us; speedup vs baseline: 2.1764x; 1.1976x over previous
//
#include <hip/hip_runtime.h>
#include <hip/hip_cooperative_groups.h>

namespace cg = cooperative_groups;

#define K_PRE 6   // pre-launched device-halting steps (bench data T~3)

// ---- ws float offsets (all float4-aligned) ----
#define O_CUM    0      // CUM[j] = cum after step j, 128 slots
#define O_DONE   128    // DONE[j], 128 slots
#define O_WSUM   256
#define O_PONDER 257
#define O_AXB    512    // ax + bh (x-half dot cache), 4096
#define O_P0     4608   // parity-0 phase-A partials (2 x 4096)
#define O_Q0     12800  // parity-1 phase-A partials (2 x 4096)
#define O_ACCO   20992  // 8192: two col-half partials of out head
#define O_ACCH   29184  // 4096
#define O_NS0    33280  // 4096 (state handoff to coop tail)
#define O_NS1    37376  // 4096

// Swizzled LDS index: +1 dword pad every 32 -> 2-way bank alias only (free).
__device__ __forceinline__ int zi(int c) { return c + (c >> 5); }

// ---------- k_step(i): [ns(i-1)+halt(i-1) redundant] + [A(i)] + [C(i-1)] ----------
// 512 blocks x 1024 thr. q = blockIdx>>8 = column quarter (i>=1) / half (i==0).
// Kernel boundary replaces grid.sync; scalar chain via per-step CUM/DONE slots.
__global__ __launch_bounds__(1024, 8) void k_step(
    int i,
    const float* __restrict__ x, const float* __restrict__ s,
    const float* __restrict__ Wh, const float* __restrict__ bh,
    const float* __restrict__ Whalt, const float* __restrict__ bhalt,
    const float* __restrict__ Wo, float* __restrict__ wsb)
{
    const int tid  = threadIdx.x;
    const int lane = tid & 63;
    const int wid  = tid >> 6;
    const int q    = blockIdx.x >> 8;                  // 0/1
    const int row  = ((blockIdx.x & 255) << 4) + wid;  // 0..4095

    __shared__ float zb[4225];
    __shared__ float red[16];

    float* pbW = wsb + ((i & 1) ? O_Q0 : O_P0);        // this step's A-partials
    const int pre = (4 - ((row + 1) & 3)) & 3;         // (row*8193+start)%4 peel, start%4==1

    if (i == 0) {
        // stage z-half: q==0 -> x (cols 1..4096), q==1 -> s (cols 4097..8192)
        const float* src = q ? s : x;
        for (int k = tid; k < 4096; k += 1024) zb[zi(k)] = src[k];
        __syncthreads();

        const float* WhR = Wh + (size_t)row * 8193;
        const int start  = q ? 4097 : 1;
        const int n4     = (4096 - pre) >> 2;
        const float4* W4 = reinterpret_cast<const float4*>(WhR + start + pre);
        float a0=0.f, a1=0.f, a2=0.f, a3=0.f;
        if (lane < pre) a0 = WhR[start + lane] * zb[zi(lane)];
        #pragma unroll 4
        for (int j = lane; j < n4; j += 64) {
            float4 wv = W4[j];
            int c = pre + 4 * j;
            a0 += wv.x * zb[zi(c)];
            a1 += wv.y * zb[zi(c + 1)];
            a2 += wv.z * zb[zi(c + 2)];
            a3 += wv.w * zb[zi(c + 3)];
        }
        for (int c = pre + 4 * n4 + lane; c < 4096; c += 64)
            a0 += WhR[start + c] * zb[zi(c)];
        float acc = (a0 + a1) + (a2 + a3);
        #pragma unroll
        for (int off = 32; off; off >>= 1) acc += __shfl_xor(acc, off, 64);
        if (lane == 0) {
            if (q == 0) {
                wsb[O_AXB + row] = acc + bh[row];      // cached x-half (+bias)
                pbW[row]         = acc + WhR[0];       // step-0 partial incl. flag col
            } else {
                pbW[4096 + row]  = acc;
            }
        }
        return;
    }

    // ---- i >= 1: idle fast path keeps the scalar chain alive ----
    const float doneB = (i >= 2) ? wsb[O_DONE + i - 2] : 0.0f;
    if (doneB != 0.0f) {
        if (blockIdx.x == 0 && tid == 0) {
            wsb[O_CUM + i - 1]  = wsb[O_CUM + i - 2];
            wsb[O_DONE + i - 1] = 1.0f;
        }
        return;
    }
    const float cumB = (i >= 2) ? wsb[O_CUM + i - 2] : 0.0f;

    // ---- ns(i-1) = pbPrev0 + pbPrev1 + bias; halt logit (redundant per block,
    //      per-thread ordering identical to r7's k_h -> same halting trajectory)
    const float* pbR  = wsb + (((i - 1) & 1) ? O_Q0 : O_P0);
    const float* bias = (i == 1) ? bh : (wsb + O_AXB);
    float4 u0 = reinterpret_cast<const float4*>(pbR)[tid];
    float4 u1 = reinterpret_cast<const float4*>(pbR + 4096)[tid];
    float4 bb = reinterpret_cast<const float4*>(bias)[tid];
    float4 hw = reinterpret_cast<const float4*>(Whalt)[tid];
    float4 nsv;
    nsv.x = u0.x + u1.x + bb.x;  nsv.y = u0.y + u1.y + bb.y;
    nsv.z = u0.z + u1.z + bb.z;  nsv.w = u0.w + u1.w + bb.w;
    { int c = 4 * tid;
      zb[zi(c)]   = nsv.x; zb[zi(c+1)] = nsv.y;
      zb[zi(c+2)] = nsv.z; zb[zi(c+3)] = nsv.w; }
    float part = hw.x*nsv.x + hw.y*nsv.y + hw.z*nsv.z + hw.w*nsv.w;
    #pragma unroll
    for (int off = 32; off; off >>= 1) part += __shfl_xor(part, off, 64);
    if (lane == 0) red[wid] = part;
    __syncthreads();                                   // zb(ns) + red ready
    float logit = bhalt[0];
    #pragma unroll
    for (int j = 0; j < 16; ++j) logit += red[j];      // identical everywhere
    const float p         = 1.0f / (1.0f + expf(-logit));
    const bool  will_halt = (cumB + p >= 0.99f) || ((i - 1) == 127);
    const float w         = will_halt ? (1.0f - cumB) : p;

    if (blockIdx.x == 0 && tid == 0) {
        wsb[O_CUM + i - 1]  = cumB + p;
        wsb[O_DONE + i - 1] = will_halt ? 1.0f : 0.0f;
        if (i == 1) wsb[O_WSUM] = w; else wsb[O_WSUM] += w;
        if (will_halt) wsb[O_PONDER] = (float)(i - 1) + 1.0f + (1.0f - cumB);
    }
    if (i == K_PRE && blockIdx.x == 256)               // handoff for coop tail
        reinterpret_cast<float4*>(wsb + (((i - 1) & 1) ? O_NS1 : O_NS0))[tid] = nsv;

    // ---- phase A(i): state-half only (x-half cached in AXB). Quarter rows.
    if (i < K_PRE && !will_halt) {
        const float* WhR = Wh + (size_t)row * 8193;
        const int start  = 4097 + 2048 * q;
        const int zo     = 2048 * q;
        const int n4     = (2048 - pre) >> 2;
        const float4* W4 = reinterpret_cast<const float4*>(WhR + start + pre);
        float a0=0.f, a1=0.f, a2=0.f, a3=0.f;
        if (lane < pre) a0 = WhR[start + lane] * zb[zi(zo + lane)];
        #pragma unroll 4
        for (int j = lane; j < n4; j += 64) {
            float4 wv = W4[j];
            int c = zo + pre + 4 * j;
            a0 += wv.x * zb[zi(c)];
            a1 += wv.y * zb[zi(c + 1)];
            a2 += wv.z * zb[zi(c + 2)];
            a3 += wv.w * zb[zi(c + 3)];
        }
        for (int c = pre + 4 * n4 + lane; c < 2048; c += 64)
            a0 += WhR[start + c] * zb[zi(zo + c)];
        float acc = (a0 + a1) + (a2 + a3);
        #pragma unroll
        for (int off = 32; off; off >>= 1) acc += __shfl_xor(acc, off, 64);
        if (lane == 0) pbW[(q << 12) + row] = acc;
    }

    // ---- phase C(i-1): accO_q[row] (+)= w * Wo[row, 2048q:+2048] @ ns
    {
        const float4* Wo4 = reinterpret_cast<const float4*>(Wo + (size_t)row * 4096);
        const int j0 = q << 9;
        float b0=0.f, b1=0.f, b2=0.f, b3=0.f;
        #pragma unroll 4
        for (int j = j0 + lane; j < j0 + 512; j += 64) {
            float4 wv = Wo4[j];
            int c = 4 * j;
            b0 += wv.x * zb[zi(c)];
            b1 += wv.y * zb[zi(c + 1)];
            b2 += wv.z * zb[zi(c + 2)];
            b3 += wv.w * zb[zi(c + 3)];
        }
        float acc2 = (b0 + b1) + (b2 + b3);
        #pragma unroll
        for (int off = 32; off; off >>= 1) acc2 += __shfl_xor(acc2, off, 64);
        if (lane == 0) {
            const int idx = O_ACCO + (q << 12) + row;
            const float v = w * acc2;
            wsb[idx] = (i == 1) ? v : (wsb[idx] + v);
            if (q == 0) {
                const int ih = O_ACCH + row;
                const float v2 = w * zb[zi(row)];
                wsb[ih] = (i == 1) ? v2 : (wsb[ih] + v2);
            }
        }
    }
}

// ---------- cooperative tail for T > K_PRE (instant uniform exit on bench data) ----------
__global__ __launch_bounds__(1024, 4) void k_tail(
    const float* __restrict__ x, const float* __restrict__ Wh,
    const float* __restrict__ bh, const float* __restrict__ Whalt,
    const float* __restrict__ bhalt, const float* __restrict__ Wo,
    float* __restrict__ wsb)
{
    cg::grid_group grid = cg::this_grid();
    if (wsb[O_DONE + K_PRE - 1] != 0.0f) return;

    const int tid  = threadIdx.x;
    const int lane = tid & 63;
    const int wid  = tid >> 6;
    const int gw   = blockIdx.x * 16 + wid;

    float* ns0 = wsb + O_NS0;
    float* ns1 = wsb + O_NS1;

    __shared__ float xl[4096];
    __shared__ float red[16];
    for (int k = tid; k < 4096; k += 1024) xl[k] = x[k];
    __syncthreads();

    const float* WhR   = Wh + (size_t)gw * 8193;
    const float4* Wo4  = reinterpret_cast<const float4*>(Wo + (size_t)gw * 4096);
    const float4* wh4  = reinterpret_cast<const float4*>(Whalt);
    const float bh_r   = bh[gw];
    const float bhalt0 = bhalt[0];

    float cum = wsb[O_CUM + K_PRE - 1];
    float accOl = 0.f, wsuml = 0.f, ponder = 0.f;

    for (int i = K_PRE; i < 128; ++i) {
        const float* st = (i & 1) ? ns0 : ns1;
        float*      nsc = (i & 1) ? ns1 : ns0;

        float acc = 0.0f;
        #pragma unroll 8
        for (int k = lane; k < 4096; k += 64) acc += WhR[1 + k] * xl[k];
        #pragma unroll 8
        for (int k = lane; k < 4096; k += 64) acc += WhR[4097 + k] * st[k];
        #pragma unroll
        for (int off = 32; off; off >>= 1) acc += __shfl_xor(acc, off, 64);
        if (lane == 0) nsc[gw] = acc + bh_r;
        grid.sync();

        const float4* ns4 = reinterpret_cast<const float4*>(nsc);
        float4 nv = ns4[tid], hw = wh4[tid];
        float part = hw.x*nv.x + hw.y*nv.y + hw.z*nv.z + hw.w*nv.w;
        #pragma unroll
        for (int off = 32; off; off >>= 1) part += __shfl_xor(part, off, 64);
        if (lane == 0) red[wid] = part;
        __syncthreads();
        float logit = bhalt0;
        #pragma unroll
        for (int j = 0; j < 16; ++j) logit += red[j];
        const float p         = 1.0f / (1.0f + expf(-logit));
        const bool  will_halt = (cum + p >= 0.99f) || (i == 127);
        const float w         = will_halt ? (1.0f - cum) : p;

        if (blockIdx.x == 0) {
            float4* aH = reinterpret_cast<float4*>(wsb + O_ACCH);
            float4 t = aH[tid];
            t.x += w*nv.x; t.y += w*nv.y; t.z += w*nv.z; t.w += w*nv.w;
            aH[tid] = t;
        }

        float b0=0.f, b1=0.f, b2=0.f, b3=0.f;
        #pragma unroll 4
        for (int j = lane; j < 1024; j += 64) {
            float4 wv = Wo4[j], qv = ns4[j];
            b0 += wv.x*qv.x; b1 += wv.y*qv.y; b2 += wv.z*qv.z; b3 += wv.w*qv.w;
        }
        float acc2 = (b0 + b1) + (b2 + b3);
        #pragma unroll
        for (int off = 32; off; off >>= 1) acc2 += __shfl_xor(acc2, off, 64);
        accOl += w * acc2;
        wsuml += w;

        if (will_halt) { ponder = (float)i + 1.0f + (1.0f - cum); break; }
        cum += p;
        grid.sync();
    }

    if (lane == 0) wsb[O_ACCO + gw] += accOl;
    if (blockIdx.x == 0 && tid == 0) {
        wsb[O_WSUM]  += wsuml;
        wsb[O_PONDER] = ponder;
    }
}

// ---------- finalize ----------
__global__ __launch_bounds__(256) void k_fin(
    const float* __restrict__ bo, float* __restrict__ out,
    const float* __restrict__ wsb)
{
    int r = blockIdx.x * 256 + threadIdx.x;            // 0..4095
    out[r]        = wsb[O_ACCO + r] + wsb[O_ACCO + 4096 + r] + wsb[O_WSUM] * bo[r];
    out[4096 + r] = wsb[O_ACCH + r];
    if (r == 0) out[8192] = wsb[O_PONDER];
}

extern "C" void kernel_launch(void* const* d_in, const int* in_sizes, int n_in,
                              void* d_out, int out_size, void* d_ws, size_t ws_size,
                              hipStream_t stream) {
    const float* x     = (const float*)d_in[0];
    const float* s     = (const float*)d_in[1];
    const float* Wh    = (const float*)d_in[2];
    const float* bh    = (const float*)d_in[3];
    const float* Whalt = (const float*)d_in[4];
    const float* bhalt = (const float*)d_in[5];
    const float* Wo    = (const float*)d_in[6];
    const float* bo    = (const float*)d_in[7];
    float* out = (float*)d_out;
    float* wsb = (float*)d_ws;

    for (int i = 0; i <= K_PRE; ++i)
        k_step<<<512, 1024, 0, stream>>>(i, x, s, Wh, bh, Whalt, bhalt, Wo, wsb);

    {   // cooperative tail for T > K_PRE
        void* args[] = { (void*)&x, (void*)&Wh, (void*)&bh, (void*)&Whalt,
                         (void*)&bhalt, (void*)&Wo, (void*)&wsb };
        hipLaunchCooperativeKernel((void*)k_tail, dim3(256), dim3(1024),
                                   args, 0, stream);
    }
    k_fin<<<16, 256, 0, stream>>>(bo, out, wsb);
}

// Round 9
// 193.229 us; speedup vs baseline: 2.8925x; 1.3290x over previous
//
#include <hip/hip_runtime.h>
#include <hip/hip_cooperative_groups.h>

namespace cg = cooperative_groups;

#define K_PRE 6   // device-gated pre-launched steps (bench data halts at T~3)

// ---- ws float offsets (all float4-aligned) ----
#define O_CUM    0      // cum after step j, 128 slots
#define O_DONE   128    // done after step j, 128 slots
#define O_WSUM   256
#define O_PONDER 257
#define O_AXB    512    // x-half dot + bh cache, 4096
#define O_P0     4608   // parity-0 A-partials (2 x 4096)
#define O_Q0     12800  // parity-1 A-partials (2 x 4096)
#define O_ACCH   20992  // hid accumulator, 4096
#define O_NS0    25088  // tail handoff state
#define O_NS1    29184

// Swizzled LDS index: +1 dword pad every 32 -> 2-way bank alias only (free).
__device__ __forceinline__ int zi(int c) { return c + (c >> 5); }

// ---------- k_step(i): [ns(i-1)+halt(i-1), redundant per block] + [A(i) quarter] ----------
// 512 blocks x 1024 thr; q = column quarter (i>=1) / half (i==0) of the row dot.
// Kernel boundaries replace grid.sync; per-step CUM/DONE slots carry the scalar chain.
__global__ __launch_bounds__(1024) void k_step(
    int i,
    const float* __restrict__ x, const float* __restrict__ s,
    const float* __restrict__ Wh, const float* __restrict__ bh,
    const float* __restrict__ Whalt, const float* __restrict__ bhalt,
    float* __restrict__ wsb)
{
    const int tid  = threadIdx.x;
    const int lane = tid & 63;
    const int wid  = tid >> 6;
    const int q    = blockIdx.x >> 8;                  // 0/1
    const int row  = ((blockIdx.x & 255) << 4) + wid;  // 0..4095

    __shared__ float zb[4225];
    __shared__ float red[16];

    const int pre = (4 - ((row + 1) & 3)) & 3;         // row*8193+start (start%4==1) peel
    float* pbW = wsb + ((i & 1) ? O_Q0 : O_P0);

    if (i == 0) {
        // q==0: cols 1..4096 (x), q==1: cols 4097..8192 (s)
        const float* src = q ? s : x;
        for (int k = tid; k < 4096; k += 1024) zb[zi(k)] = src[k];
        __syncthreads();

        const float* WhR = Wh + (size_t)row * 8193;
        const int start  = q ? 4097 : 1;
        const int n4     = (4096 - pre) >> 2;
        const float4* W4 = reinterpret_cast<const float4*>(WhR + start + pre);
        float a0=0.f, a1=0.f, a2=0.f, a3=0.f;
        if (lane < pre) a0 = WhR[start + lane] * zb[zi(lane)];
        #pragma unroll 8
        for (int j = lane; j < n4; j += 64) {
            float4 wv = W4[j];
            int c = pre + 4 * j;
            a0 += wv.x * zb[zi(c)];
            a1 += wv.y * zb[zi(c + 1)];
            a2 += wv.z * zb[zi(c + 2)];
            a3 += wv.w * zb[zi(c + 3)];
        }
        for (int c = pre + 4 * n4 + lane; c < 4096; c += 64)
            a0 += WhR[start + c] * zb[zi(c)];
        float acc = (a0 + a1) + (a2 + a3);
        #pragma unroll
        for (int off = 32; off; off >>= 1) acc += __shfl_xor(acc, off, 64);
        if (lane == 0) {
            if (q == 0) {
                wsb[O_AXB + row] = acc + bh[row];      // cached x-half (+bias)
                pbW[row]         = acc + WhR[0];       // step-0 partial incl. flag col
            } else {
                pbW[4096 + row]  = acc;
            }
        }
        return;
    }

    // ---- idle fast path keeps the scalar chain alive ----
    const float doneB = (i >= 2) ? wsb[O_DONE + i - 2] : 0.0f;
    if (doneB != 0.0f) {
        if (blockIdx.x == 0 && tid == 0) {
            wsb[O_CUM + i - 1]  = wsb[O_CUM + i - 2];
            wsb[O_DONE + i - 1] = 1.0f;
        }
        return;
    }
    const float cumB = (i >= 2) ? wsb[O_CUM + i - 2] : 0.0f;

    // ---- ns(i-1) = pb0 + pb1 + bias; halt logit (redundant, order == r8) ----
    const float* pbR  = wsb + (((i - 1) & 1) ? O_Q0 : O_P0);
    const float* bias = (i == 1) ? bh : (wsb + O_AXB);
    float4 u0 = reinterpret_cast<const float4*>(pbR)[tid];
    float4 u1 = reinterpret_cast<const float4*>(pbR + 4096)[tid];
    float4 bb = reinterpret_cast<const float4*>(bias)[tid];
    float4 hw = reinterpret_cast<const float4*>(Whalt)[tid];
    float4 nsv;
    nsv.x = u0.x + u1.x + bb.x;  nsv.y = u0.y + u1.y + bb.y;
    nsv.z = u0.z + u1.z + bb.z;  nsv.w = u0.w + u1.w + bb.w;
    if ((tid >> 9) == q) {                             // stage this block's quarter
        int lc = 4 * tid - 2048 * q;                   // 0..2047
        zb[zi(lc)]   = nsv.x; zb[zi(lc+1)] = nsv.y;
        zb[zi(lc+2)] = nsv.z; zb[zi(lc+3)] = nsv.w;
    }
    float part = hw.x*nsv.x + hw.y*nsv.y + hw.z*nsv.z + hw.w*nsv.w;
    #pragma unroll
    for (int off = 32; off; off >>= 1) part += __shfl_xor(part, off, 64);
    if (lane == 0) red[wid] = part;
    __syncthreads();                                   // zb quarter + red ready
    float logit = bhalt[0];
    #pragma unroll
    for (int j = 0; j < 16; ++j) logit += red[j];      // identical everywhere
    const float p         = 1.0f / (1.0f + expf(-logit));
    const bool  will_halt = (cumB + p >= 0.99f) || ((i - 1) == 127);
    const float w         = will_halt ? (1.0f - cumB) : p;

    if (blockIdx.x == 0 && tid == 0) {
        wsb[O_CUM + i - 1]  = cumB + p;
        wsb[O_DONE + i - 1] = will_halt ? 1.0f : 0.0f;
        if (i == 1) wsb[O_WSUM] = w; else wsb[O_WSUM] += w;
        if (will_halt) wsb[O_PONDER] = (float)(i - 1) + 1.0f + (1.0f - cumB);
    }
    // hid accumulator: block 0 owns it (f4 per thread, per-step order preserved)
    if (blockIdx.x == 0) {
        float4* aH = reinterpret_cast<float4*>(wsb + O_ACCH);
        if (i == 1) {
            float4 t; t.x = w*nsv.x; t.y = w*nsv.y; t.z = w*nsv.z; t.w = w*nsv.w;
            aH[tid] = t;
        } else {
            float4 t = aH[tid];
            t.x += w*nsv.x; t.y += w*nsv.y; t.z += w*nsv.z; t.w += w*nsv.w;
            aH[tid] = t;
        }
    }
    if (i == K_PRE && blockIdx.x == 1)                 // handoff for coop tail
        reinterpret_cast<float4*>(wsb + (((i - 1) & 1) ? O_NS1 : O_NS0))[tid] = nsv;

    // ---- A(i): state-quarter dot (x-half cached in AXB) ----
    if (i < K_PRE && !will_halt) {
        const float* WhR = Wh + (size_t)row * 8193;
        const int start  = 4097 + 2048 * q;
        const int n4     = (2048 - pre) >> 2;
        const float4* W4 = reinterpret_cast<const float4*>(WhR + start + pre);
        float a0=0.f, a1=0.f, a2=0.f, a3=0.f;
        if (lane < pre) a0 = WhR[start + lane] * zb[zi(lane)];
        #pragma unroll 8
        for (int j = lane; j < n4; j += 64) {
            float4 wv = W4[j];
            int c = pre + 4 * j;
            a0 += wv.x * zb[zi(c)];
            a1 += wv.y * zb[zi(c + 1)];
            a2 += wv.z * zb[zi(c + 2)];
            a3 += wv.w * zb[zi(c + 3)];
        }
        for (int c = pre + 4 * n4 + lane; c < 2048; c += 64)
            a0 += WhR[start + c] * zb[zi(c)];
        float acc = (a0 + a1) + (a2 + a3);
        #pragma unroll
        for (int off = 32; off; off >>= 1) acc += __shfl_xor(acc, off, 64);
        if (lane == 0) pbW[(q << 12) + row] = acc;
    }
}

// ---------- cooperative tail for T > K_PRE (instant uniform exit on bench data) ----------
__global__ __launch_bounds__(1024, 4) void k_tail(
    const float* __restrict__ x, const float* __restrict__ Wh,
    const float* __restrict__ bh, const float* __restrict__ Whalt,
    const float* __restrict__ bhalt, float* __restrict__ wsb)
{
    cg::grid_group grid = cg::this_grid();
    if (wsb[O_DONE + K_PRE - 1] != 0.0f) return;

    const int tid  = threadIdx.x;
    const int lane = tid & 63;
    const int wid  = tid >> 6;
    const int gw   = blockIdx.x * 16 + wid;

    float* ns0 = wsb + O_NS0;
    float* ns1 = wsb + O_NS1;

    __shared__ float xl[4096];
    __shared__ float red[16];
    for (int k = tid; k < 4096; k += 1024) xl[k] = x[k];
    __syncthreads();

    const float* WhR   = Wh + (size_t)gw * 8193;
    const float4* wh4  = reinterpret_cast<const float4*>(Whalt);
    const float bh_r   = bh[gw];
    const float bhalt0 = bhalt[0];

    float cum = wsb[O_CUM + K_PRE - 1];
    float wsuml = 0.f, ponder = 0.f;

    for (int i = K_PRE; i < 128; ++i) {
        const float* st = (i & 1) ? ns0 : ns1;
        float*      nsc = (i & 1) ? ns1 : ns0;

        float acc = 0.0f;
        #pragma unroll 8
        for (int k = lane; k < 4096; k += 64) acc += WhR[1 + k] * xl[k];
        #pragma unroll 8
        for (int k = lane; k < 4096; k += 64) acc += WhR[4097 + k] * st[k];
        #pragma unroll
        for (int off = 32; off; off >>= 1) acc += __shfl_xor(acc, off, 64);
        if (lane == 0) nsc[gw] = acc + bh_r;
        grid.sync();

        const float4* ns4 = reinterpret_cast<const float4*>(nsc);
        float4 nv = ns4[tid], hw = wh4[tid];
        float part = hw.x*nv.x + hw.y*nv.y + hw.z*nv.z + hw.w*nv.w;
        #pragma unroll
        for (int off = 32; off; off >>= 1) part += __shfl_xor(part, off, 64);
        if (lane == 0) red[wid] = part;
        __syncthreads();
        float logit = bhalt0;
        #pragma unroll
        for (int j = 0; j < 16; ++j) logit += red[j];
        const float p         = 1.0f / (1.0f + expf(-logit));
        const bool  will_halt = (cum + p >= 0.99f) || (i == 127);
        const float w         = will_halt ? (1.0f - cum) : p;

        if (blockIdx.x == 0) {                          // hid accumulator
            float4* aH = reinterpret_cast<float4*>(wsb + O_ACCH);
            float4 t = aH[tid];
            t.x += w*nv.x; t.y += w*nv.y; t.z += w*nv.z; t.w += w*nv.w;
            aH[tid] = t;
        }
        wsuml += w;

        if (will_halt) { ponder = (float)i + 1.0f + (1.0f - cum); break; }
        cum += p;
        grid.sync();
    }

    if (blockIdx.x == 0 && tid == 0) {
        wsb[O_WSUM]  += wsuml;
        wsb[O_PONDER] = ponder;
    }
}

// ---------- k_out: out = Wo @ hid + wsum*bo  (Wo read exactly once) ----------
__global__ __launch_bounds__(1024) void k_out(
    const float* __restrict__ Wo, const float* __restrict__ bo,
    const float* __restrict__ wsb, float* __restrict__ out)
{
    const int tid  = threadIdx.x;
    const int lane = tid & 63;
    const int wid  = tid >> 6;
    const int row  = blockIdx.x * 16 + wid;            // 256 blocks -> 0..4095

    __shared__ float zb[4225];
    for (int k = tid; k < 4096; k += 1024) zb[zi(k)] = wsb[O_ACCH + k];
    __syncthreads();

    const float4* Wo4 = reinterpret_cast<const float4*>(Wo + (size_t)row * 4096);
    float b0=0.f, b1=0.f, b2=0.f, b3=0.f;
    #pragma unroll 8
    for (int j = lane; j < 1024; j += 64) {
        float4 wv = Wo4[j];
        int c = 4 * j;
        b0 += wv.x * zb[zi(c)];
        b1 += wv.y * zb[zi(c + 1)];
        b2 += wv.z * zb[zi(c + 2)];
        b3 += wv.w * zb[zi(c + 3)];
    }
    float acc = (b0 + b1) + (b2 + b3);
    #pragma unroll
    for (int off = 32; off; off >>= 1) acc += __shfl_xor(acc, off, 64);
    if (lane == 0) out[row] = acc + wsb[O_WSUM] * bo[row];

    const int gtid = blockIdx.x * 1024 + tid;
    if (gtid < 4096) out[4096 + gtid] = wsb[O_ACCH + gtid];
    if (gtid == 0)   out[8192] = wsb[O_PONDER];
}

extern "C" void kernel_launch(void* const* d_in, const int* in_sizes, int n_in,
                              void* d_out, int out_size, void* d_ws, size_t ws_size,
                              hipStream_t stream) {
    const float* x     = (const float*)d_in[0];
    const float* s     = (const float*)d_in[1];
    const float* Wh    = (const float*)d_in[2];
    const float* bh    = (const float*)d_in[3];
    const float* Whalt = (const float*)d_in[4];
    const float* bhalt = (const float*)d_in[5];
    const float* Wo    = (const float*)d_in[6];
    const float* bo    = (const float*)d_in[7];
    float* out = (float*)d_out;
    float* wsb = (float*)d_ws;

    for (int i = 0; i <= K_PRE; ++i)
        k_step<<<512, 1024, 0, stream>>>(i, x, s, Wh, bh, Whalt, bhalt, wsb);

    {   // cooperative tail for T > K_PRE
        void* args[] = { (void*)&x, (void*)&Wh, (void*)&bh, (void*)&Whalt,
                         (void*)&bhalt, (void*)&wsb };
        hipLaunchCooperativeKernel((void*)k_tail, dim3(256), dim3(1024),
                                   args, 0, stream);
    }
    k_out<<<256, 1024, 0, stream>>>(Wo, bo, wsb, out);
}